// Round 7
// baseline (890.700 us; speedup 1.0000x reference)
//
#include <hip/hip_runtime.h>
#include <math.h>

// Problem constants (B=10240, D=512, M=8, L=3)
#define BB   10240
#define DD   512
#define MM   8

typedef _Float16 h8 __attribute__((ext_vector_type(8)));
typedef float    f4 __attribute__((ext_vector_type(4)));

// ---------------- fp32 -> fp16 convert (8 elems/thread) ----------------
__global__ void __launch_bounds__(256) cvt_f32_f16(const float* __restrict__ s,
                                                   _Float16* __restrict__ d, int n8) {
    int i = blockIdx.x * 256 + threadIdx.x;
    if (i >= n8) return;
    const float4* sp = (const float4*)s + (size_t)i * 2;
    float4 a = sp[0], b = sp[1];
    h8 o = { (_Float16)a.x, (_Float16)a.y, (_Float16)a.z, (_Float16)a.w,
             (_Float16)b.x, (_Float16)b.y, (_Float16)b.z, (_Float16)b.w };
    *(h8*)(d + (size_t)i * 8) = o;
}

// ---------------- no-LDS split-K GEMM, XCD-pinned, TLP-saturated ----------------
// partial[b,i] = sum_m pW[b,m] sum_{j in K-half} W[m,i,j] x[b,j]
// R6 lesson: compiler sinks explicit register double-buffers (VGPR 84, JIT
// loads) -> per-wave util ~10% and only 2.5 waves/SIMD of TLP. Fix: buy TLP.
// Split-K=2 via blockIdx.z doubles waves (10240 = 32/CU demand); wave tile
// back to 32x32 (mt=2,nt=2, R5-proven 64 VGPR -> 8 waves/SIMD allowed).
// grid (16,80,2) x-fastest: linear blk % 8 == XCD, col tiles c,c+8 pinned ->
// per-XCD W slice 512 KB, L2-resident (R5 verified FETCH 698->45 MB).
// NO barriers, NO LDS, NO atomics: z=0 stores fp32 partial to acc0 (d_out),
// z=1 stores fp16 partial to acc1 (ws slab); finish_k adds them.
__global__ void __launch_bounds__(256, 8) gemm_sk(
    const _Float16* __restrict__ xh,   // (B,512) fp16
    const _Float16* __restrict__ Wh,   // (8,512,512) fp16
    const float*  __restrict__ pW,     // (B,8)
    float*    __restrict__ acc0,       // (B,512) fp32 partial (z==0)
    _Float16* __restrict__ acc1)       // (B,512) fp16 partial (z==1)
{
    const int tid  = threadIdx.x;
    const int lane = tid & 63;
    const int wm   = tid >> 6;         // 0..3: waves stack on rows
    const int ln16 = lane & 15, quad = lane >> 4;
    const int bn0  = blockIdx.x * 32;  // 16 col tiles; blk%8 == XCD
    const int bm0  = blockIdx.y * 128;
    const int jc0  = blockIdx.z * 4;   // K-half: jc in [jc0, jc0+4)

    // per-lane pW for this wave's 2 A-row groups (row = bm0+wm*32+mt*16+ln16)
    _Float16 pwh[2][8];
    #pragma unroll
    for (int mt = 0; mt < 2; ++mt) {
        const float* pp = pW + (size_t)(bm0 + wm * 32 + mt * 16 + ln16) * MM;
        float4 p0 = *(const float4*)pp;
        float4 p1 = *(const float4*)(pp + 4);
        pwh[mt][0] = (_Float16)p0.x; pwh[mt][1] = (_Float16)p0.y;
        pwh[mt][2] = (_Float16)p0.z; pwh[mt][3] = (_Float16)p0.w;
        pwh[mt][4] = (_Float16)p1.x; pwh[mt][5] = (_Float16)p1.y;
        pwh[mt][6] = (_Float16)p1.z; pwh[mt][7] = (_Float16)p1.w;
    }

    const _Float16* arow[2];
    #pragma unroll
    for (int mt = 0; mt < 2; ++mt)
        arow[mt] = xh + (size_t)(bm0 + wm * 32 + mt * 16 + ln16) * DD;
    const _Float16* brow[2];
    #pragma unroll
    for (int nt = 0; nt < 2; ++nt)
        brow[nt] = Wh + (size_t)(bn0 + nt * 16 + ln16) * DD;

    f4 acc[2][2] = {};

    #pragma unroll
    for (int j2 = 0; j2 < 4; ++j2) {
        const int k0 = (jc0 + j2) * 64 + quad * 8;

        h8 af[2][2];                       // [ks][mt], reused across 8 m
        #pragma unroll
        for (int ks = 0; ks < 2; ++ks)
            #pragma unroll
            for (int mt = 0; mt < 2; ++mt)
                af[ks][mt] = *(const h8*)(arow[mt] + k0 + ks * 32);

        #pragma unroll
        for (int mi = 0; mi < 8; ++mi) {
            h8 bf[2][2];                   // [ks][nt]
            #pragma unroll
            for (int ks = 0; ks < 2; ++ks)
                #pragma unroll
                for (int nt = 0; nt < 2; ++nt)
                    bf[ks][nt] = *(const h8*)(brow[nt] + (size_t)mi * (DD * DD)
                                              + k0 + ks * 32);
            #pragma unroll
            for (int ks = 0; ks < 2; ++ks)
                #pragma unroll
                for (int mt = 0; mt < 2; ++mt) {
                    h8 as = af[ks][mt] * pwh[mt][mi];   // v_pk_mul_f16 x4
                    #pragma unroll
                    for (int nt = 0; nt < 2; ++nt)
                        acc[mt][nt] = __builtin_amdgcn_mfma_f32_16x16x32_f16(
                            as, bf[ks][nt], acc[mt][nt], 0, 0, 0);
                }
        }
    }

    // ---- plain stores of raw partial (each element written exactly once) ----
    if (blockIdx.z == 0) {
        #pragma unroll
        for (int mt = 0; mt < 2; ++mt)
            #pragma unroll
            for (int nt = 0; nt < 2; ++nt) {
                const int i = bn0 + nt * 16 + ln16;
                #pragma unroll
                for (int r = 0; r < 4; ++r) {
                    int b = bm0 + wm * 32 + mt * 16 + quad * 4 + r;
                    acc0[(size_t)b * DD + i] = acc[mt][nt][r];
                }
            }
    } else {
        #pragma unroll
        for (int mt = 0; mt < 2; ++mt)
            #pragma unroll
            for (int nt = 0; nt < 2; ++nt) {
                const int i = bn0 + nt * 16 + ln16;
                #pragma unroll
                for (int r = 0; r < 4; ++r) {
                    int b = bm0 + wm * 32 + mt * 16 + quad * 4 + r;
                    acc1[(size_t)b * DD + i] = (_Float16)acc[mt][nt][r];
                }
            }
    }
}

// ---------------- finish: sum partials + gate + bias (+ LN + ELU) ----------------
// h[b,i] = gW[b,i]*(acc0[b,i]+acc1[b,i]) + gb[b,i]*sum_m pb[b,m]*bs[m,i]
// DO_LN: LN(no affine)+ELU -> fp16 outh; else fp32 outf (may alias acc0).
template <int DO_LN>
__global__ void __launch_bounds__(256) finish_k(
    const float* __restrict__ acc0,      // (B,512) fp32 partial
    const _Float16* __restrict__ acc1,   // (B,512) fp16 partial
    const float* __restrict__ gW,    // (B,512)
    const float* __restrict__ gb,    // (B,512)
    const float* __restrict__ pb,    // (B,8)
    const float* __restrict__ bsv,   // (8,512)
    float* __restrict__ outf, _Float16* __restrict__ outh) {
    const int w    = threadIdx.x >> 6;
    const int lane = threadIdx.x & 63;
    const int row  = blockIdx.x * 4 + w;
    const int i0   = lane * 8;

    const float* ap = acc0 + (size_t)row * DD + i0;
    float a[8];
    *(float4*)a       = *(const float4*)ap;
    *(float4*)(a + 4) = *(const float4*)(ap + 4);
    h8 a1 = *(const h8*)(acc1 + (size_t)row * DD + i0);
    #pragma unroll
    for (int j = 0; j < 8; ++j) a[j] += (float)a1[j];

    float4 q0 = *(const float4*)(pb + (size_t)row * MM);
    float4 q1 = *(const float4*)(pb + (size_t)row * MM + 4);
    float pbv[8] = { q0.x, q0.y, q0.z, q0.w, q1.x, q1.y, q1.z, q1.w };

    float bias[8] = {};
    #pragma unroll
    for (int m = 0; m < 8; ++m) {
        const float* bp = bsv + m * DD + i0;
        float4 b0 = *(const float4*)bp, b1 = *(const float4*)(bp + 4);
        float bb[8] = { b0.x, b0.y, b0.z, b0.w, b1.x, b1.y, b1.z, b1.w };
        #pragma unroll
        for (int j = 0; j < 8; ++j) bias[j] += pbv[m] * bb[j];
    }

    const float* gwp = gW + (size_t)row * DD + i0;
    const float* gbp = gb + (size_t)row * DD + i0;
    float4 w0 = *(const float4*)gwp, w1 = *(const float4*)(gwp + 4);
    float4 g0 = *(const float4*)gbp, g1 = *(const float4*)(gbp + 4);
    float gw[8] = { w0.x, w0.y, w0.z, w0.w, w1.x, w1.y, w1.z, w1.w };
    float gg[8] = { g0.x, g0.y, g0.z, g0.w, g1.x, g1.y, g1.z, g1.w };

    float h[8];
    #pragma unroll
    for (int j = 0; j < 8; ++j) h[j] = gw[j] * a[j] + gg[j] * bias[j];

    if (DO_LN) {
        float s = 0.f, q = 0.f;
        #pragma unroll
        for (int j = 0; j < 8; ++j) { s += h[j]; q += h[j] * h[j]; }
        #pragma unroll
        for (int off = 1; off < 64; off <<= 1) {
            s += __shfl_xor(s, off);
            q += __shfl_xor(q, off);
        }
        float mu   = s * (1.0f / 512.0f);
        float var  = q * (1.0f / 512.0f) - mu * mu;
        float rstd = rsqrtf(var + 1e-5f);
        h8 o;
        #pragma unroll
        for (int j = 0; j < 8; ++j) {
            float t = (h[j] - mu) * rstd;
            t = t > 0.0f ? t : expm1f(t);
            o[j] = (_Float16)t;
        }
        *(h8*)(outh + (size_t)row * DD + i0) = o;
    } else {
        float* op = outf + (size_t)row * DD + i0;
        *(float4*)op       = make_float4(h[0], h[1], h[2], h[3]);
        *(float4*)(op + 4) = make_float4(h[4], h[5], h[6], h[7]);
    }
}

extern "C" void kernel_launch(void* const* d_in, const int* in_sizes, int n_in,
                              void* d_out, int out_size, void* d_ws, size_t ws_size,
                              hipStream_t stream) {
    const float* x   = (const float*)d_in[0];   // (B,512)
    const float* Ws  = (const float*)d_in[1];   // (3,8,512,512)
    const float* bs  = (const float*)d_in[2];   // (3,8,512)
    const float* pWs = (const float*)d_in[3];   // (3,B,8)
    const float* pbs = (const float*)d_in[4];   // (3,B,8)
    const float* gWs = (const float*)d_in[5];   // (3,B,512,1)
    const float* gbs = (const float*)d_in[6];   // (3,B,512)
    float* out = (float*)d_out;                 // (B,512); doubles as fp32 partial

    // workspace: Wh 12.58 MB + xh 10.49 MB + acc1 10.49 MB = 32 MiB exactly
    _Float16* Wh   = (_Float16*)d_ws;
    _Float16* xh   = Wh + (size_t)3 * MM * DD * DD;
    _Float16* ac1  = xh + (size_t)BB * DD;

    const int wsl = MM * DD * DD;
    const int bsl = MM * DD;
    const int pl  = BB * MM;
    const int gl  = BB * DD;

    cvt_f32_f16<<<3072, 256, 0, stream>>>(Ws, Wh, 786432);   // 3*8*512*512/8
    cvt_f32_f16<<<2560, 256, 0, stream>>>(x, xh, 655360);    // B*512/8

    dim3 gg(DD / 32, BB / 128, 2);       // (16, 80, 2): x-fastest, blk%8 == XCD

    // layer 0
    gemm_sk<<<gg, 256, 0, stream>>>(xh, Wh, pWs, out, ac1);
    finish_k<1><<<BB / 4, 256, 0, stream>>>(out, ac1, gWs, gbs, pbs, bs,
                                            nullptr, xh);
    // layer 1
    gemm_sk<<<gg, 256, 0, stream>>>(xh, Wh + wsl, pWs + pl, out, ac1);
    finish_k<1><<<BB / 4, 256, 0, stream>>>(out, ac1, gWs + gl, gbs + gl,
                                            pbs + pl, bs + bsl, nullptr, xh);
    // layer 2 (no LN, fp32 out in place)
    gemm_sk<<<gg, 256, 0, stream>>>(xh, Wh + 2 * wsl, pWs + 2 * pl, out, ac1);
    finish_k<0><<<BB / 4, 256, 0, stream>>>(out, ac1, gWs + 2 * gl, gbs + 2 * gl,
                                            pbs + 2 * pl, bs + 2 * bsl, out, nullptr);
}